// Round 12
// baseline (1619.932 us; speedup 1.0000x reference)
//
#include <hip/hip_runtime.h>

// ROUND 12 = DECISIVE STORE-PATH SPLIT (distinctly-NAMED probes; R8's template
// ablates collapsed to one rocprof name and were misread twice).
//   conv_v5_nostore  x12 reps: R6 K-loop+staging, NO stores (asm keep-alive)
//   conv_v6_scatter  x 2 reps: NO K-loop, R6 scatter epilogue only (zeros)
//   conv_v7_lin      x 5 reps: same 126MB store volume, fully linear addresses
//   conv_main        (R6 proven 99us) runs LAST -> correct output.
// Interpretation: divide probe dur by its rep factor.

using bf16x8 = __attribute__((ext_vector_type(8))) __bf16;
using f32x4  = __attribute__((ext_vector_type(4))) float;
using f32x16 = __attribute__((ext_vector_type(16))) float;

constexpr int CIN  = 128;
constexpr int HW   = 64;
constexpr int COUT = 256;
constexpr int OW   = 62;
constexpr int NS   = 62 * 62;          // 3844
constexpr int NTOT = 32 * NS;          // 123008
constexpr int KTOT = 9 * CIN;          // 1152
constexpr int BM = 128, BN = 128, BK = 64;
constexpr int NT = KTOT / BK;          // 18
constexpr int NWG = 2 * (NTOT / BN);   // 1922
constexpr unsigned OUT_ELEMS = (unsigned)NTOT * COUT;   // 31489024 floats

constexpr size_t AP_BYTES = (size_t)COUT * KTOT * 2;
constexpr size_t XP_BYTES = (size_t)32 * HW * HW * CIN * 2;
constexpr size_t WS_NEEDED = AP_BYTES + XP_BYTES;

constexpr int BUF  = 32768;
constexpr int BOFF = 16384;

__device__ __forceinline__ unsigned short f2bf(float f) {
  unsigned u = __float_as_uint(f);
  u += 0x7fffu + ((u >> 16) & 1u);
  return (unsigned short)(u >> 16);
}
__device__ __forceinline__ unsigned pack2(float a, float b) {
  return (unsigned)f2bf(a) | ((unsigned)f2bf(b) << 16);
}
__device__ __forceinline__ void gld16(const void* g, void* l) {
  __builtin_amdgcn_global_load_lds(
      (const __attribute__((address_space(1))) unsigned int*)g,
      (__attribute__((address_space(3))) unsigned int*)l, 16, 0, 0);
}

// ---------------- prepack kernels ----------------

__global__ __launch_bounds__(256)
void prepack_w(const float* __restrict__ w, unsigned* __restrict__ ap32) {
  const int idx = blockIdx.x * 256 + threadIdx.x;
  const int co  = idx / 576;
  const int k2  = idx - co * 576;
  const int k   = k2 * 2;
  const int tap = k >> 7;
  const int ci  = k & 127;
  ap32[idx] = pack2(w[(co * 128 + ci) * 9 + tap], w[(co * 128 + ci + 1) * 9 + tap]);
}

__global__ __launch_bounds__(256)
void prepack_x(const float* __restrict__ x, unsigned* __restrict__ xp32) {
  const int bh = blockIdx.x;
  const int b  = bh >> 6, h = bh & 63;
  const int t  = threadIdx.x;
  const int c  = t & 63;
  const int w0 = (t >> 6) * 16;
  const float* p0 = x + (((size_t)(b * 128 + 2 * c) * HW) + h) * HW + w0;
  const float* p1 = p0 + (size_t)HW * HW;
  float r0[16], r1[16];
#pragma unroll
  for (int j = 0; j < 4; ++j) {
    *reinterpret_cast<float4*>(&r0[j * 4]) = reinterpret_cast<const float4*>(p0)[j];
    *reinterpret_cast<float4*>(&r1[j * 4]) = reinterpret_cast<const float4*>(p1)[j];
  }
  unsigned* o = xp32 + ((size_t)bh * HW + w0) * 64 + c;
#pragma unroll
  for (int j = 0; j < 16; ++j)
    o[j * 64] = pack2(r0[j], r1[j]);
}

// ---------------- shared helpers for main/probes ----------------

struct BlockCtx {
  int co_base, n_base;
  int aoff[4]; unsigned xoff[4];
  int sA[4], abase, bbase, cl, gl;
};

__device__ __forceinline__ void init_ctx(BlockCtx& c, int f, int lane, int wid) {
  int wg;
  {
    constexpr int q = NWG / 8, r = NWG % 8;
    const int xc = f % 8, p = f / 8;
    wg = (xc < r ? xc * (q + 1) : r * (q + 1) + (xc - r) * q) + p;
  }
  c.co_base = (wg & 1) * BM;
  c.n_base  = (wg >> 1) * BN;
  const int l3  = lane >> 3;
  const int sw8 = ((lane & 7) ^ l3) * 8;
#pragma unroll
  for (int q = 0; q < 4; ++q) {
    const int rr = wid * 32 + q * 8 + l3;
    c.aoff[q] = (c.co_base + rr) * KTOT + sw8;
    const unsigned n  = c.n_base + rr;
    const unsigned bi = n / NS;
    const unsigned s0 = n - bi * NS;
    const unsigned oh = s0 / OW;
    const unsigned ww = s0 - oh * OW;
    c.xoff[q] = ((bi * HW + oh) * HW + ww) * CIN + sw8;
  }
  c.cl = lane & 31;
  c.gl = lane >> 5;
#pragma unroll
  for (int kf = 0; kf < 4; ++kf)
    c.sA[kf] = ((kf * 2 + c.gl) ^ (lane & 7)) * 16;
  const int wm = wid >> 1, wn = wid & 1;
  c.abase = (wm * 64 + c.cl) * 128;
  c.bbase = BOFF + (wn * 64 + c.cl) * 128;
}

__device__ __forceinline__ void stage_step(const BlockCtx& c, int wid,
                                           const unsigned short* Ap,
                                           const unsigned short* Xp,
                                           int t, char* dst) {
  const int tap = t >> 1;
  const int kh  = tap / 3;
  const int kw  = tap - kh * 3;
  const int ak  = tap * CIN + (t & 1) * 64;
  const int xk  = (kh * HW + kw) * CIN + (t & 1) * 64;
#pragma unroll
  for (int q = 0; q < 4; ++q)
    gld16(Ap + c.aoff[q] + ak, dst + (wid * 32 + q * 8) * 128);
#pragma unroll
  for (int q = 0; q < 4; ++q)
    gld16(Xp + c.xoff[q] + xk, dst + BOFF + (wid * 32 + q * 8) * 128);
}

__device__ __forceinline__ void kloop(const BlockCtx& c, int wid,
                                      const unsigned short* Ap,
                                      const unsigned short* Xp,
                                      char* lds, f32x16 (&acc)[2][2]) {
  stage_step(c, wid, Ap, Xp, 0, lds);
#pragma unroll
  for (int t = 0; t < NT; ++t) {
    const char* cur = lds + (t & 1) * BUF;
    asm volatile("s_waitcnt vmcnt(0)" ::: "memory");
    __builtin_amdgcn_s_barrier();
    if (t + 1 < NT) stage_step(c, wid, Ap, Xp, t + 1, lds + ((t + 1) & 1) * BUF);

    bf16x8 a[2][4], b[2][4];
#pragma unroll
    for (int mt = 0; mt < 2; ++mt)
#pragma unroll
      for (int kf = 0; kf < 4; ++kf)
        a[mt][kf] = *reinterpret_cast<const bf16x8*>(cur + c.abase + mt * 4096 + c.sA[kf]);
#pragma unroll
    for (int nt = 0; nt < 2; ++nt)
#pragma unroll
      for (int kf = 0; kf < 4; ++kf)
        b[nt][kf] = *reinterpret_cast<const bf16x8*>(cur + c.bbase + nt * 4096 + c.sA[kf]);

#pragma unroll
    for (int kf = 0; kf < 4; ++kf)
#pragma unroll
      for (int mt = 0; mt < 2; ++mt)
#pragma unroll
        for (int nt = 0; nt < 2; ++nt)
          acc[mt][nt] = __builtin_amdgcn_mfma_f32_32x32x16_bf16(
              a[mt][kf], b[nt][kf], acc[mt][nt], 0, 0, 0);
  }
}

__device__ __forceinline__ void epilogue(const BlockCtx& c, int wid,
                                         float* out, const f32x16 (&acc)[2][2]) {
  const int wm = wid >> 1, wn = wid & 1;
#pragma unroll
  for (int mt = 0; mt < 2; ++mt)
#pragma unroll
    for (int nt = 0; nt < 2; ++nt) {
      const unsigned n  = c.n_base + wn * 64 + nt * 32 + c.cl;
      const unsigned b2 = n / NS;
      const unsigned s2 = n - b2 * NS;
      float* op = out + (size_t)b2 * (COUT * NS) + s2
                      + (size_t)(c.co_base + wm * 64 + mt * 32 + c.gl * 4) * NS;
#pragma unroll
      for (int r = 0; r < 16; ++r)
        op[((r & 3) + 8 * (r >> 2)) * NS] = acc[mt][nt][r];
    }
}

// ---------------- main kernel (R6, proven 99us) ----------------

__global__ __launch_bounds__(256, 2)
void conv_main(const unsigned short* __restrict__ Ap,
               const unsigned short* __restrict__ Xp,
               float* __restrict__ out) {
  __shared__ __align__(16) char lds[2 * BUF];
  const int lane = threadIdx.x & 63, wid = threadIdx.x >> 6;
  BlockCtx c; init_ctx(c, blockIdx.x, lane, wid);
  f32x16 acc[2][2] = {};
  kloop(c, wid, Ap, Xp, lds, acc);
  epilogue(c, wid, out, acc);
}

// ---------------- probe V5: K-loop only, no stores, x12 ----------------

__global__ __launch_bounds__(256, 2)
void conv_v5_nostore(const unsigned short* __restrict__ Ap,
                     const unsigned short* __restrict__ Xp,
                     float* __restrict__ out) {
  __shared__ __align__(16) char lds[2 * BUF];
  const int lane = threadIdx.x & 63, wid = threadIdx.x >> 6;
  BlockCtx c; init_ctx(c, blockIdx.x, lane, wid);
  f32x16 acc[2][2] = {};
  for (int rep = 0; rep < 12; ++rep)
    kloop(c, wid, Ap, Xp, lds, acc);
  // keep acc live without storing (rule #17)
#pragma unroll
  for (int mt = 0; mt < 2; ++mt)
#pragma unroll
    for (int nt = 0; nt < 2; ++nt)
#pragma unroll
      for (int r = 0; r < 16; ++r)
        asm volatile("" :: "v"(acc[mt][nt][r]));
  (void)out;
}

// ---------------- probe V6: scatter stores only, x2 ----------------

__global__ __launch_bounds__(256, 2)
void conv_v6_scatter(const unsigned short* __restrict__ Ap,
                     const unsigned short* __restrict__ Xp,
                     float* __restrict__ out) {
  const int lane = threadIdx.x & 63, wid = threadIdx.x >> 6;
  BlockCtx c; init_ctx(c, blockIdx.x, lane, wid);
  f32x16 acc[2][2] = {};
  (void)Ap; (void)Xp;
  for (int rep = 0; rep < 2; ++rep)
    epilogue(c, wid, out, acc);     // zeros; overwritten by conv_main later
}

// ---------------- probe V7: linear stores, same volume, x5 ----------------

__global__ __launch_bounds__(256, 2)
void conv_v7_lin(float* __restrict__ out) {
  const unsigned base = blockIdx.x * 4096u + threadIdx.x;   // float4 index
  const float4 z = {0.f, 0.f, 0.f, 0.f};
  for (int rep = 0; rep < 5; ++rep) {
#pragma unroll
    for (int p = 0; p < 16; ++p) {
      const unsigned i4 = base + p * 256u;
      if (i4 * 4u < OUT_ELEMS)
        reinterpret_cast<float4*>(out)[i4] = z;              // overwritten later
    }
  }
}

// ---------------- fallback (no-ws path, round-1 proven) ----------------

__global__ __launch_bounds__(256)
void conv_fallback(const float* __restrict__ x, const float* __restrict__ w,
                   float* __restrict__ out) {
  __shared__ __align__(16) unsigned short As[128 * 32];
  __shared__ __align__(16) unsigned short Bs[128 * 32];

  const int t    = threadIdx.x;
  const int lane = t & 63;
  const int wid  = t >> 6;
  const int wm   = wid >> 1;
  const int wn   = wid & 1;
  const int co_base = blockIdx.x * 128;
  const int n_base  = blockIdx.y * 128;

  const int bn  = t & 127;
  const int bg0 = t >> 7;
  const unsigned n0   = n_base + bn;
  const unsigned bidx = n0 / NS;
  const unsigned s0   = n0 - bidx * NS;
  const unsigned oh   = s0 / OW;
  const unsigned ow   = s0 - oh * OW;
  const float* xb = x + (bidx * (CIN * HW * HW) + oh * HW + ow);

  const int am  = t & 127;
  const int ag0 = (t >> 7) * 2;
  const float* wb = w + (co_base + am) * KTOT;

  f32x4 acc[4][4] = {};

  for (int ks = 0; ks < 36; ++ks) {
    const int tap = ks >> 2;
    const int ci0 = (ks & 3) * 32;
    const int kh  = tap / 3;
    const int kw  = tap - kh * 3;
    const int xo  = kh * HW + kw;

    float av[2][8], bv[2][8];
#pragma unroll
    for (int gi = 0; gi < 2; ++gi) {
      const int g = ag0 + gi;
#pragma unroll
      for (int j = 0; j < 8; ++j)
        av[gi][j] = wb[(ci0 + g * 8 + j) * 9 + tap];
    }
#pragma unroll
    for (int gi = 0; gi < 2; ++gi) {
      const int g = bg0 + gi * 2;
#pragma unroll
      for (int j = 0; j < 8; ++j)
        bv[gi][j] = xb[xo + (ci0 + g * 8 + j) * (HW * HW)];
    }

    __syncthreads();

#pragma unroll
    for (int gi = 0; gi < 2; ++gi) {
      const int g = ag0 + gi;
      uint4 pv;
      pv.x = pack2(av[gi][0], av[gi][1]);
      pv.y = pack2(av[gi][2], av[gi][3]);
      pv.z = pack2(av[gi][4], av[gi][5]);
      pv.w = pack2(av[gi][6], av[gi][7]);
      *reinterpret_cast<uint4*>(&As[am * 32 + ((g ^ ((am >> 1) & 3)) << 3)]) = pv;
    }
#pragma unroll
    for (int gi = 0; gi < 2; ++gi) {
      const int g = bg0 + gi * 2;
      uint4 pv;
      pv.x = pack2(bv[gi][0], bv[gi][1]);
      pv.y = pack2(bv[gi][2], bv[gi][3]);
      pv.z = pack2(bv[gi][4], bv[gi][5]);
      pv.w = pack2(bv[gi][6], bv[gi][7]);
      *reinterpret_cast<uint4*>(&Bs[bn * 32 + ((g ^ ((bn >> 1) & 3)) << 3)]) = pv;
    }

    __syncthreads();

    bf16x8 af[4], bfr[4];
    const int g = lane >> 4;
#pragma unroll
    for (int mi = 0; mi < 4; ++mi) {
      const int m = wm * 64 + mi * 16 + (lane & 15);
      af[mi] = *reinterpret_cast<const bf16x8*>(&As[m * 32 + ((g ^ ((m >> 1) & 3)) << 3)]);
    }
#pragma unroll
    for (int ni = 0; ni < 4; ++ni) {
      const int nn = wn * 64 + ni * 16 + (lane & 15);
      bfr[ni] = *reinterpret_cast<const bf16x8*>(&Bs[nn * 32 + ((g ^ ((nn >> 1) & 3)) << 3)]);
    }
#pragma unroll
    for (int mi = 0; mi < 4; ++mi)
#pragma unroll
      for (int ni = 0; ni < 4; ++ni)
        acc[mi][ni] = __builtin_amdgcn_mfma_f32_16x16x32_bf16(af[mi], bfr[ni],
                                                              acc[mi][ni], 0, 0, 0);
  }

#pragma unroll
  for (int ni = 0; ni < 4; ++ni) {
    const unsigned n  = n_base + wn * 64 + ni * 16 + (lane & 15);
    const unsigned b2 = n / NS;
    const unsigned s2 = n - b2 * NS;
    float* op = out + (size_t)b2 * (COUT * NS) + s2
                    + (size_t)(co_base + wm * 64 + (lane >> 4) * 4) * NS;
#pragma unroll
    for (int mi = 0; mi < 4; ++mi)
#pragma unroll
      for (int r = 0; r < 4; ++r)
        op[(mi * 16 + r) * NS] = acc[mi][ni][r];
  }
}

extern "C" void kernel_launch(void* const* d_in, const int* in_sizes, int n_in,
                              void* d_out, int out_size, void* d_ws, size_t ws_size,
                              hipStream_t stream) {
  const float* x = (const float*)d_in[0];
  const float* w = (const float*)d_in[1];
  float* out = (float*)d_out;

  if (ws_size >= WS_NEEDED) {
    unsigned* ap32 = (unsigned*)d_ws;
    unsigned short* Ap = (unsigned short*)d_ws;
    unsigned short* Xp = (unsigned short*)((char*)d_ws + AP_BYTES);
    unsigned* xp32 = (unsigned*)Xp;
    prepack_w<<<576, 256, 0, stream>>>(w, ap32);
    prepack_x<<<32 * HW, 256, 0, stream>>>(x, xp32);
    // probes (outputs garbage/zeros; conv_main rewrites everything)
    conv_v5_nostore<<<dim3(NWG), 256, 0, stream>>>(Ap, Xp, out);
    conv_v6_scatter<<<dim3(NWG), 256, 0, stream>>>(Ap, Xp, out);
    conv_v7_lin<<<dim3(NWG), 256, 0, stream>>>(out);
    conv_main<<<dim3(NWG), 256, 0, stream>>>(Ap, Xp, out);
  } else {
    conv_fallback<<<dim3(2, NTOT / 128), 256, 0, stream>>>(x, w, out);
  }
}

// Round 13
// 114.828 us; speedup vs baseline: 14.1074x; 14.1074x over previous
//
#include <hip/hip_runtime.h>

// Implicit-GEMM conv2d via bf16 MFMA (32x32x16), ws pre-pack.
// R13: 256x256 tile (halves L2 traffic vs R6's 128x128 -> floor ~47us),
// BK=64, 512 thr / 8 waves (2M x 4N), wave tile 128x64, acc 4x2 f32x16.
// K-split phases: per K-tile, 2 confirmation points (kh=0,1):
//   vmcnt(4) -> barrier -> stage A-half(t+1,kh) -> ds_read B,A -> lgkmcnt(0)
//   -> 8 MFMA (mh=0) -> stage B-half(t+1,kh) -> 8 MFMA (mh=1)
// Stage order AK0,BK0,AK1,BK1; every half has >=3 phases in flight; vmcnt
// never 0 except final tile. 36 barriers total. LDS 4 x 32KB = 128KB.
// Half-tile = contiguous 16KB block in R7's verified paired-row layout.
//   A' [256][1152] bf16 (k = tap*128+ci)   xp [32][64][64][128] bf16 NHWC

using bf16x8 = __attribute__((ext_vector_type(8))) __bf16;
using f32x4  = __attribute__((ext_vector_type(4))) float;
using f32x16 = __attribute__((ext_vector_type(16))) float;

constexpr int CIN  = 128;
constexpr int HW   = 64;
constexpr int COUT = 256;
constexpr int OW   = 62;
constexpr int NS   = 62 * 62;          // 3844
constexpr int NTOT = 32 * NS;          // 123008
constexpr int KTOT = 9 * CIN;          // 1152
constexpr int BN = 256;
constexpr int NT = 18;                 // K-tiles of 64
constexpr int NBLK = (NTOT + BN - 1) / BN;   // 481

constexpr size_t AP_BYTES = (size_t)COUT * KTOT * 2;            // 589824
constexpr size_t XP_BYTES = (size_t)32 * HW * HW * CIN * 2;     // 33554432
constexpr size_t WS_NEEDED = AP_BYTES + XP_BYTES;

__device__ __forceinline__ unsigned short f2bf(float f) {
  unsigned u = __float_as_uint(f);
  u += 0x7fffu + ((u >> 16) & 1u);     // RNE
  return (unsigned short)(u >> 16);
}
__device__ __forceinline__ unsigned pack2(float a, float b) {
  return (unsigned)f2bf(a) | ((unsigned)f2bf(b) << 16);
}
__device__ __forceinline__ void gld16(const void* g, void* l) {
  __builtin_amdgcn_global_load_lds(
      (const __attribute__((address_space(1))) unsigned int*)g,
      (__attribute__((address_space(3))) unsigned int*)l, 16, 0, 0);
}

// ---------------- prepack kernels (unchanged, proven) ----------------

__global__ __launch_bounds__(256)
void prepack_w(const float* __restrict__ w, unsigned* __restrict__ ap32) {
  const int idx = blockIdx.x * 256 + threadIdx.x;
  const int co  = idx / 576;
  const int k2  = idx - co * 576;
  const int k   = k2 * 2;
  const int tap = k >> 7;
  const int ci  = k & 127;
  ap32[idx] = pack2(w[(co * 128 + ci) * 9 + tap], w[(co * 128 + ci + 1) * 9 + tap]);
}

__global__ __launch_bounds__(256)
void prepack_x(const float* __restrict__ x, unsigned* __restrict__ xp32) {
  const int bh = blockIdx.x;
  const int b  = bh >> 6, h = bh & 63;
  const int t  = threadIdx.x;
  const int c  = t & 63;
  const int w0 = (t >> 6) * 16;
  const float* p0 = x + (((size_t)(b * 128 + 2 * c) * HW) + h) * HW + w0;
  const float* p1 = p0 + (size_t)HW * HW;
  float r0[16], r1[16];
#pragma unroll
  for (int j = 0; j < 4; ++j) {
    *reinterpret_cast<float4*>(&r0[j * 4]) = reinterpret_cast<const float4*>(p0)[j];
    *reinterpret_cast<float4*>(&r1[j * 4]) = reinterpret_cast<const float4*>(p1)[j];
  }
  unsigned* o = xp32 + ((size_t)bh * HW + w0) * 64 + c;
#pragma unroll
  for (int j = 0; j < 16; ++j)
    o[j * 64] = pack2(r0[j], r1[j]);
}

// ---------------- main kernel ----------------

__global__ __launch_bounds__(512, 2)
void conv_main(const unsigned short* __restrict__ Ap,
               const unsigned short* __restrict__ Xp,
               float* __restrict__ out) {
  // LDS: Abuf[2] 32KB each @0, @32K; Bbuf[2] @64K, @96K.
  // Each buf = 2 kh-half blocks of 16KB; half block = R7 paired-row layout:
  // 128B line = 2 rows of 32 bf16; slotpos = (row&1)*4 + (g ^ (line&3)).
  __shared__ __align__(16) char lds[131072];

  const int tid  = threadIdx.x;
  const int lane = tid & 63;
  const int wid  = tid >> 6;       // 0..7
  const int wm   = wid & 1;        // M half (co 128 rows)
  const int wn   = wid >> 1;       // N slice (64 cols), 0..3

  // bijective XCD swizzle over 481 blocks
  int wg;
  {
    const int f = blockIdx.x;
    constexpr int q = NBLK / 8, r = NBLK % 8;    // 60, 1
    const int xc = f % 8, p = f / 8;
    wg = (xc < r ? xc * (q + 1) : r * (q + 1) + (xc - r) * q) + p;
  }
  const int n_base = wg * BN;

  // ---- staging decode (R7-verbatim): chunk ch = wid*2+q covers rows ch*16..+15
  const int lrow2 = ((lane >> 3) << 1) + ((lane >> 2) & 1);
  const int g8    = ((lane & 3) ^ ((lane >> 3) & 3)) * 8;
  int aoff[2];
  unsigned xoff[2];
#pragma unroll
  for (int q = 0; q < 2; ++q) {
    const int rr = (wid * 2 + q) * 16 + lrow2;     // 0..255
    aoff[q] = rr * KTOT + g8;                      // co row (BM=256 = all co)
    unsigned n = n_base + rr;
    if (n >= NTOT) n = NTOT - 1;                   // tail block clamp
    const unsigned bi = n / NS;
    const unsigned s0 = n - bi * NS;
    const unsigned oh = s0 / OW;
    const unsigned ww = s0 - oh * OW;
    xoff[q] = ((bi * HW + oh) * HW + ww) * CIN + g8;
  }

  // ---- fragment addressing (R7-verbatim paired-row) ----
  const int cl = lane & 31;
  const int gl = lane >> 5;
  const int q4 = (cl >> 1) & 3;
  const int sw0 = ((gl)     ^ q4) * 16;
  const int sw1 = ((2 + gl) ^ q4) * 16;
  const int ABASE = (wm * 64 + (cl >> 1)) * 128 + (cl & 1) * 64;  // +mt*2048
  const int BBASE = (wn * 32 + (cl >> 1)) * 128 + (cl & 1) * 64;  // +nt*2048

  f32x16 acc[4][2] = {};

  auto STAGE_A = [&](int t, int kh) {
    char* dst = lds + (t & 1) * 32768 + kh * 16384;
    const int ak = t * 64 + kh * 32;
#pragma unroll
    for (int q = 0; q < 2; ++q)
      gld16(Ap + aoff[q] + ak, dst + (wid * 2 + q) * 1024);
  };
  auto STAGE_B = [&](int t, int kh) {
    char* dst = lds + 65536 + (t & 1) * 32768 + kh * 16384;
    const int q32 = t * 2 + kh;                    // 32-k chunk index 0..35
    const int tap = q32 >> 2, ci0 = (q32 & 3) * 32;
    const int kh3 = tap / 3, kw3 = tap - kh3 * 3;
    const int xk  = (kh3 * HW + kw3) * CIN + ci0;
#pragma unroll
    for (int q = 0; q < 2; ++q)
      gld16(Xp + xoff[q] + xk, dst + (wid * 2 + q) * 1024);
  };

  // prologue: tile0's four halves, in ledger order
  STAGE_A(0, 0); STAGE_B(0, 0); STAGE_A(0, 1); STAGE_B(0, 1);

#pragma unroll
  for (int t = 0; t < NT; ++t) {
    const char* Ab = lds + (t & 1) * 32768;
    const char* Bb = lds + 65536 + (t & 1) * 32768;
#pragma unroll
    for (int kh = 0; kh < 2; ++kh) {
      // confirmation point: the two oldest in-flight halves are (A,B)[t][kh]
      if (kh == 0 || t < NT - 1)
        asm volatile("s_waitcnt vmcnt(4)" ::: "memory");
      else
        asm volatile("s_waitcnt vmcnt(0)" ::: "memory");
      __builtin_amdgcn_s_barrier();
      __builtin_amdgcn_sched_barrier(0);
      if (t + 1 < NT) STAGE_A(t + 1, kh);

      const char* Abh = Ab + kh * 16384;
      const char* Bbh = Bb + kh * 16384;

      bf16x8 b[2][2];
#pragma unroll
      for (int nt = 0; nt < 2; ++nt) {
        b[nt][0] = *reinterpret_cast<const bf16x8*>(Bbh + BBASE + nt * 2048 + sw0);
        b[nt][1] = *reinterpret_cast<const bf16x8*>(Bbh + BBASE + nt * 2048 + sw1);
      }
#pragma unroll
      for (int mh = 0; mh < 2; ++mh) {
        if (mh == 1 && t + 1 < NT) STAGE_B(t + 1, kh);
        bf16x8 a[2][2];
#pragma unroll
        for (int j = 0; j < 2; ++j) {
          a[j][0] = *reinterpret_cast<const bf16x8*>(Abh + ABASE + (mh * 2 + j) * 2048 + sw0);
          a[j][1] = *reinterpret_cast<const bf16x8*>(Abh + ABASE + (mh * 2 + j) * 2048 + sw1);
        }
        asm volatile("s_waitcnt lgkmcnt(0)" ::: "memory");
        __builtin_amdgcn_sched_barrier(0);
        __builtin_amdgcn_s_setprio(1);
#pragma unroll
        for (int kf = 0; kf < 2; ++kf)
#pragma unroll
          for (int j = 0; j < 2; ++j)
#pragma unroll
            for (int nt = 0; nt < 2; ++nt)
              acc[mh * 2 + j][nt] = __builtin_amdgcn_mfma_f32_32x32x16_bf16(
                  a[j][kf], b[nt][kf], acc[mh * 2 + j][nt], 0, 0, 0);
        __builtin_amdgcn_s_setprio(0);
      }
    }
  }

  // ---- epilogue (proven scatter): col=lane&31, row=(r&3)+8*(r>>2)+4*gl ----
#pragma unroll
  for (int mt = 0; mt < 4; ++mt)
#pragma unroll
    for (int nt = 0; nt < 2; ++nt) {
      const unsigned n = n_base + wn * 64 + nt * 32 + cl;
      if (n >= NTOT) continue;
      const unsigned b2 = n / NS;
      const unsigned s2 = n - b2 * NS;
      float* op = out + (size_t)b2 * (COUT * NS) + s2
                      + (size_t)(wm * 128 + mt * 32 + gl * 4) * NS;
#pragma unroll
      for (int r = 0; r < 16; ++r)
        op[((r & 3) + 8 * (r >> 2)) * NS] = acc[mt][nt][r];
    }
}

// ---------------- fallback (no-ws path, round-1 proven) ----------------

__global__ __launch_bounds__(256)
void conv_fallback(const float* __restrict__ x, const float* __restrict__ w,
                   float* __restrict__ out) {
  __shared__ __align__(16) unsigned short As[128 * 32];
  __shared__ __align__(16) unsigned short Bs[128 * 32];

  const int t    = threadIdx.x;
  const int lane = t & 63;
  const int wid  = t >> 6;
  const int wm   = wid >> 1;
  const int wn   = wid & 1;
  const int co_base = blockIdx.x * 128;
  const int n_base  = blockIdx.y * 128;

  const int bn  = t & 127;
  const int bg0 = t >> 7;
  const unsigned n0   = n_base + bn;
  const unsigned bidx = n0 / NS;
  const unsigned s0   = n0 - bidx * NS;
  const unsigned oh   = s0 / OW;
  const unsigned ow   = s0 - oh * OW;
  const float* xb = x + (bidx * (CIN * HW * HW) + oh * HW + ow);

  const int am  = t & 127;
  const int ag0 = (t >> 7) * 2;
  const float* wb = w + (co_base + am) * KTOT;

  f32x4 acc[4][4] = {};

  for (int ks = 0; ks < 36; ++ks) {
    const int tap = ks >> 2;
    const int ci0 = (ks & 3) * 32;
    const int kh  = tap / 3;
    const int kw  = tap - kh * 3;
    const int xo  = kh * HW + kw;

    float av[2][8], bv[2][8];
#pragma unroll
    for (int gi = 0; gi < 2; ++gi) {
      const int g = ag0 + gi;
#pragma unroll
      for (int j = 0; j < 8; ++j)
        av[gi][j] = wb[(ci0 + g * 8 + j) * 9 + tap];
    }
#pragma unroll
    for (int gi = 0; gi < 2; ++gi) {
      const int g = bg0 + gi * 2;
#pragma unroll
      for (int j = 0; j < 8; ++j)
        bv[gi][j] = xb[xo + (ci0 + g * 8 + j) * (HW * HW)];
    }

    __syncthreads();

#pragma unroll
    for (int gi = 0; gi < 2; ++gi) {
      const int g = ag0 + gi;
      uint4 pv;
      pv.x = pack2(av[gi][0], av[gi][1]);
      pv.y = pack2(av[gi][2], av[gi][3]);
      pv.z = pack2(av[gi][4], av[gi][5]);
      pv.w = pack2(av[gi][6], av[gi][7]);
      *reinterpret_cast<uint4*>(&As[am * 32 + ((g ^ ((am >> 1) & 3)) << 3)]) = pv;
    }
#pragma unroll
    for (int gi = 0; gi < 2; ++gi) {
      const int g = bg0 + gi * 2;
      uint4 pv;
      pv.x = pack2(bv[gi][0], bv[gi][1]);
      pv.y = pack2(bv[gi][2], bv[gi][3]);
      pv.z = pack2(bv[gi][4], bv[gi][5]);
      pv.w = pack2(bv[gi][6], bv[gi][7]);
      *reinterpret_cast<uint4*>(&Bs[bn * 32 + ((g ^ ((bn >> 1) & 3)) << 3)]) = pv;
    }

    __syncthreads();

    bf16x8 af[4], bfr[4];
    const int g = lane >> 4;
#pragma unroll
    for (int mi = 0; mi < 4; ++mi) {
      const int m = wm * 64 + mi * 16 + (lane & 15);
      af[mi] = *reinterpret_cast<const bf16x8*>(&As[m * 32 + ((g ^ ((m >> 1) & 3)) << 3)]);
    }
#pragma unroll
    for (int ni = 0; ni < 4; ++ni) {
      const int nn = wn * 64 + ni * 16 + (lane & 15);
      bfr[ni] = *reinterpret_cast<const bf16x8*>(&Bs[nn * 32 + ((g ^ ((nn >> 1) & 3)) << 3)]);
    }
#pragma unroll
    for (int mi = 0; mi < 4; ++mi)
#pragma unroll
      for (int ni = 0; ni < 4; ++ni)
        acc[mi][ni] = __builtin_amdgcn_mfma_f32_16x16x32_bf16(af[mi], bfr[ni],
                                                              acc[mi][ni], 0, 0, 0);
  }

#pragma unroll
  for (int ni = 0; ni < 4; ++ni) {
    const unsigned n  = n_base + wn * 64 + ni * 16 + (lane & 15);
    const unsigned b2 = n / NS;
    const unsigned s2 = n - b2 * NS;
    float* op = out + (size_t)b2 * (COUT * NS) + s2
                    + (size_t)(co_base + wm * 64 + (lane >> 4) * 4) * NS;
#pragma unroll
    for (int mi = 0; mi < 4; ++mi)
#pragma unroll
      for (int r = 0; r < 4; ++r)
        op[(mi * 16 + r) * NS] = acc[mi][ni][r];
  }
}

extern "C" void kernel_launch(void* const* d_in, const int* in_sizes, int n_in,
                              void* d_out, int out_size, void* d_ws, size_t ws_size,
                              hipStream_t stream) {
  const float* x = (const float*)d_in[0];   // [32,128,64,64]
  const float* w = (const float*)d_in[1];   // [256,128,3,3]
  float* out = (float*)d_out;               // [32,256,62,62]

  if (ws_size >= WS_NEEDED) {
    unsigned* ap32 = (unsigned*)d_ws;
    unsigned short* Ap = (unsigned short*)d_ws;
    unsigned short* Xp = (unsigned short*)((char*)d_ws + AP_BYTES);
    unsigned* xp32 = (unsigned*)Xp;
    prepack_w<<<576, 256, 0, stream>>>(w, ap32);
    prepack_x<<<32 * HW, 256, 0, stream>>>(x, xp32);
    conv_main<<<dim3(NBLK), 512, 0, stream>>>(Ap, Xp, out);
  } else {
    conv_fallback<<<dim3(2, NTOT / 128), 256, 0, stream>>>(x, w, out);
  }
}